// Round 5
// baseline (421.021 us; speedup 1.0000x reference)
//
#include <hip/hip_runtime.h>
#include <hip/hip_bf16.h>
#include <math.h>

// Model: out[b,p,c] = sum_l Kmat[p,l] * x[b,l,c] + bias[p]
// Kmat = Weff_s @ D + (Weff_t - Weff_s) @ (D@T),  Weff = (W @ M)/512
// Output is F32 (resolved r0-r4).
//
// R9 (this round):
//  - gemm_main_t: R8's counted-vmcnt pipeline was NOT latency-bound, it was
//    LDS-READ-THROUGHPUT bound (128 KB LDS reads per k-tile per CU vs 620 cyc
//    of MFMA -> 20% MfmaUtil ceiling; R6/R7/R8 all measured 17-21%). Fix the
//    bytes/FLOP: BM=256 x BN=256 x BK=64, 8 waves of 128x64 each
//    (bytes/FLOP 1/42.7 vs 1/32; 32 MFMA per 12 ds_reads per phase).
//    2 LDS buffers (128 KB), 2 barriers/iter, vmcnt(8). Same k-order ->
//    bit-identical output. Grid 3x128=384, XCD-chunked.
//  - prep1: xpose (memory-bound) + build_weff (compute-bound) fused into one
//    launch (block-index discriminated) -> co-scheduled, one less launch.
//  - build_kmat unchanged (verified).

#define BATCH 64
#define SEQ 1024
#define CH 512
#define PRED 720
#define INV_SQRT2 0.70710678118654752440f

typedef __attribute__((ext_vector_type(4))) float floatx4;
typedef __attribute__((ext_vector_type(8))) short bf16x8;

// ---- workspace layout (bytes) ----
#define KBF_OFF   0ull          // bf16 Kmat[768][1024]     = 1,572,864 B
#define BIAS_OFF  1572864ull    // f32 bias[768]            =     3,072 B
#define WEFFS_OFF 2624512ull    // f32 WeffS[720][512]      = 1,474,560 B
#define WEFFT_OFF 4099072ull    // f32 WeffT[720][512]      = 1,474,560 B
#define XT_OFF    5573632ull    // bf16 xT[64][512][1024]   = 67,108,864 B
#define WS_NEED   (XT_OFF + 67108864ull)

// ---------------- helpers ----------------
__device__ __forceinline__ void async_ld16(const void* g, void* l) {
    __builtin_amdgcn_global_load_lds((const __attribute__((address_space(1))) void*)g,
                                     (__attribute__((address_space(3))) void*)l, 16, 0, 0);
}

__device__ __forceinline__ short f2bf(float f) {
    __hip_bfloat16 h = __float2bfloat16(f);
    return *reinterpret_cast<short*>(&h);
}

// ---------------- prep1: fused xpose + build_weff ----------------
// Blocks [0, nx):       xpose  x[b,l,c] f32 -> xT[b,c,l] bf16   (nx = 8192)
// Blocks [nx, nx+384):  build_weff (192 blocks x 2 branches flattened = 384? no:
//                       192 blocks: 8 n-tiles x 12 p-tiles x 2 (s/t))
// Both use 256 threads; shared smem union (max 16.7 KB).
__global__ void __launch_bounds__(256) prep1(
    const float* __restrict__ x, short* __restrict__ xT,
    const float* __restrict__ Ws_in, const float* __restrict__ Wt_in,
    float* __restrict__ outS, float* __restrict__ outT) {
    __shared__ __align__(16) char smem[64 * 65 * 4];   // 16,640 B, unioned
    int t = threadIdx.x;
    int nx = (int)gridDim.x - 192;
    if ((int)blockIdx.x < nx) {
        // ---- xpose (verified r5) ----
        float (*lds)[65] = reinterpret_cast<float(*)[65]>(smem);
        int idx = blockIdx.x;
        int l0 = (idx & 15) * 64, c0 = ((idx >> 4) & 7) * 64, b = idx >> 7;
        const float* xb = x + (size_t)b * SEQ * CH;
        int row4 = t >> 4, cq = t & 15;
#pragma unroll
        for (int i = 0; i < 4; i++) {
            int row = row4 + i * 16;
            floatx4 v = __builtin_nontemporal_load(reinterpret_cast<const floatx4*>(
                xb + (size_t)(l0 + row) * CH + c0 + cq * 4));
#pragma unroll
            for (int e = 0; e < 4; e++) lds[row][cq * 4 + e] = v[e];
        }
        __syncthreads();
        size_t outb = (size_t)b * CH * SEQ;
#pragma unroll
        for (int r = 0; r < 2; r++) {
            int u = r * 256 + t;
            int lr = u & 7, c = u >> 3;
            bf16x8 s;
#pragma unroll
            for (int e = 0; e < 8; e++) s[e] = f2bf(lds[lr * 8 + e][c]);
            *reinterpret_cast<bf16x8*>(&xT[outb + (size_t)(c0 + c) * SEQ + l0 + lr * 8]) = s;
        }
    } else {
        // ---- build_weff (verified r6/r8, inline DCT) ----
        float (*wlds)[65] = reinterpret_cast<float(*)[65]>(smem);                    // [32][65]
        float (*mlds)[64] = reinterpret_cast<float(*)[64]>(smem + 32 * 65 * 4);      // [32][64]
        int wb = (int)blockIdx.x - nx;        // 0..191
        const float* W = (wb >= 96) ? Wt_in : Ws_in;
        float* out     = (wb >= 96) ? outT  : outS;
        int wz = wb % 96;
        int n0 = (wz & 7) * 64;               // 8 n-tiles
        int p0 = (wz >> 3) * 64;              // 12 p-tiles
        int tx = t & 15, ty = t >> 4;
        float a[4][4] = {};
        for (int kb = 0; kb < 512; kb += 32) {
            __syncthreads();
            {
                int pp = t >> 2, kk0 = (t & 3) * 8;
                int prow = min(p0 + pp, PRED - 1);
                const float* wsrc = &W[(size_t)prow * 512 + kb + kk0];
#pragma unroll
                for (int e = 0; e < 8; e++) wlds[kk0 + e][pp] = wsrc[e];
            }
            {
                int kk = t >> 3, nn0 = (t & 7) * 8;
                int k = kb + kk;
                float scale = (k == 0) ? 0.04419417382415922f : 0.0625f;
                scale *= (1.0f / 512.0f);
#pragma unroll
                for (int e = 0; e < 8; e++) {
                    int n = n0 + nn0 + e;
                    int m = ((2 * n + 1) * k) & 2047;
                    float ang = (float)m * (float)(M_PI / 1024.0);
                    mlds[kk][nn0 + e] = cosf(ang) * scale;
                }
            }
            __syncthreads();
#pragma unroll
            for (int kk = 0; kk < 32; kk++) {
                floatx4 wv = *reinterpret_cast<const floatx4*>(&wlds[kk][ty * 4]);
                floatx4 mv = *reinterpret_cast<const floatx4*>(&mlds[kk][tx * 4]);
#pragma unroll
                for (int i = 0; i < 4; i++)
#pragma unroll
                    for (int j = 0; j < 4; j++)
                        a[i][j] += wv[i] * mv[j];
            }
        }
#pragma unroll
        for (int i = 0; i < 4; i++) {
            int p = p0 + ty * 4 + i;
            if (p < PRED) {
                floatx4 v = {a[i][0], a[i][1], a[i][2], a[i][3]};
                *reinterpret_cast<floatx4*>(&out[(size_t)p * 512 + n0 + tx * 4]) = v;
            }
        }
    }
}

// ---------------- Kmat build (banded D@T analytic, verified) ----------------
__device__ __forceinline__ int tcnt(int j, int l) {
    if (l == 0)    return max(0, 13 - j);
    if (l == 1023) return max(0, j - 1010);
    int d = l - j; if (d < 0) d = -d;
    return (d <= 12) ? 1 : 0;
}

__global__ void build_kmat(const float* __restrict__ Ws, const float* __restrict__ Wt,
                           const float* __restrict__ bs, const float* __restrict__ bt,
                           __hip_bfloat16* __restrict__ Kbf, float* __restrict__ bias) {
    int idx = blockIdx.x * 256 + threadIdx.x;   // 768*1024
    int p = idx >> 10, l = idx & 1023;
    if (p >= PRED) { Kbf[idx] = __float2bfloat16(0.0f); return; }
    if (l == 0) bias[p] = bs[p] + bt[p];
    float v = INV_SQRT2 * Ws[(size_t)p * 512 + (l >> 1)];
    int jlo = max(0, l - 12), jhi = min(1023, l + 12);
    float acc = 0.f;
    for (int n = (jlo >> 1); n <= (jhi >> 1); n++) {
        int c = tcnt(2 * n, l) + tcnt(2 * n + 1, l);
        if (c) acc += (Wt[(size_t)p * 512 + n] - Ws[(size_t)p * 512 + n]) * (float)c;
    }
    v += acc * (INV_SQRT2 / 25.0f);
    Kbf[idx] = __float2bfloat16(v);
}

// ---------------- main GEMM: BM=256 BN=256 BK=64, 8 waves of 128x64 ----------------
// Flattened batched GEMM: A = Kbf[768][1024], B = xT viewed [32768][1024],
// out[b][p][c]. 2 LDS buffers (64 KB each), counted vmcnt(8), 2 raw barriers
// per iter (stage(it+2) must follow compute(it) with 2 buffers). LDS layout:
// slot s (16B) = A[((s>>7)<<4)+(s&15)][((s>>6)&1)*32+((s>>4)&3)*8 ..+8];
// fragment read byte = rowgrp*2048 + ks*1024 + lane*16 -> lane-linear,
// conflict-free. k-accumulation order identical to R5-R8 -> bit-identical.
__global__ void __launch_bounds__(512, 2) gemm_main_t(
    const short* __restrict__ Kbf, const short* __restrict__ xT,
    const float* __restrict__ bias, float* __restrict__ out) {
    // [buf 0..1][A 32KB | B 32KB] = 128 KB
    __shared__ __align__(16) short ldsbuf[2 * 32768];
    int t = threadIdx.x;
    int wave = t >> 6, lane = t & 63;
    int bid = blockIdx.x;                       // 384 blocks
    int work = (bid & 7) * 48 + (bid >> 3);     // XCD-chunked, bijective
    int mt = work % 3;                          // A panel (256 rows)
    int nt = work / 3;                          // B panel (256 n-rows), 0..127
    int wm = wave >> 2, wn = wave & 3;          // 2x4 waves of 128x64
    const short* Ag = Kbf + (size_t)mt * 256 * 1024;
    const short* Bg = xT + (size_t)nt * 256 * 1024;

    // per-thread staged-slot source offsets (4 slots each for A and for B)
    size_t so[4];
#pragma unroll
    for (int a = 0; a < 4; a++) {
        int s = a * 512 + t;
        so[a] = (size_t)(((s >> 7) << 4) + (s & 15)) * 1024
              + ((s >> 6) & 1) * 32 + ((s >> 4) & 3) * 8;
    }

    floatx4 acc[8][4];
#pragma unroll
    for (int i = 0; i < 8; i++)
#pragma unroll
        for (int j = 0; j < 4; j++)
            acc[i][j] = (floatx4){0.f, 0.f, 0.f, 0.f};

#define STAGE(bufidx, k0v)                                                     \
    {                                                                          \
        char* base_ = (char*)ldsbuf + (bufidx) * 65536;                        \
        _Pragma("unroll")                                                      \
        for (int a = 0; a < 4; a++)                                            \
            async_ld16(Ag + so[a] + (k0v), base_ + a * 8192 + wave * 1024);    \
        _Pragma("unroll")                                                      \
        for (int a = 0; a < 4; a++)                                            \
            async_ld16(Bg + so[a] + (k0v),                                     \
                       base_ + 32768 + a * 8192 + wave * 1024);                \
    }

#define COMPUTE(cbp)                                                           \
    {                                                                          \
        _Pragma("unroll")                                                      \
        for (int ks = 0; ks < 2; ks++) {                                       \
            bf16x8 af[8], bf[4];                                               \
            _Pragma("unroll")                                                  \
            for (int i = 0; i < 8; i++)                                        \
                af[i] = *reinterpret_cast<const bf16x8*>(                      \
                    (cbp) + ((wm * 8 + i) << 11) + (ks << 10) + (lane << 4));  \
            _Pragma("unroll")                                                  \
            for (int j = 0; j < 4; j++)                                        \
                bf[j] = *reinterpret_cast<const bf16x8*>(                      \
                    (cbp) + 32768 + ((wn * 4 + j) << 11) + (ks << 10) +        \
                    (lane << 4));                                              \
            __builtin_amdgcn_s_setprio(1);                                     \
            _Pragma("unroll")                                                  \
            for (int i = 0; i < 8; i++)                                        \
                _Pragma("unroll")                                              \
                for (int j = 0; j < 4; j++)                                    \
                    acc[i][j] = __builtin_amdgcn_mfma_f32_16x16x32_bf16(       \
                        af[i], bf[j], acc[i][j], 0, 0, 0);                     \
            __builtin_amdgcn_s_setprio(0);                                     \
        }                                                                      \
    }

    // prologue: stage k-tiles 0,1 into bufs 0,1
    STAGE(0, 0);
    STAGE(1, 64);

    for (int it = 0; it < 15; ++it) {
        // outstanding: stage(it+1)'s 8 loads; vmcnt(8) => stage(it) landed.
        asm volatile("s_waitcnt vmcnt(8)" ::: "memory");
        __builtin_amdgcn_s_barrier();
        __builtin_amdgcn_sched_barrier(0);
        const char* cbp = (const char*)ldsbuf + (it & 1) * 65536;
        COMPUTE(cbp);
        __builtin_amdgcn_sched_barrier(0);
        __builtin_amdgcn_s_barrier();           // all waves done reading buf[it&1]
        __builtin_amdgcn_sched_barrier(0);
        if (it < 14) STAGE(it & 1, (it + 2) * 64);
    }
    // peeled last k-tile (15) from buf 1
    asm volatile("s_waitcnt vmcnt(0)" ::: "memory");
    __builtin_amdgcn_s_barrier();
    __builtin_amdgcn_sched_barrier(0);
    {
        const char* cbp = (const char*)ldsbuf + 65536;
        COMPUTE(cbp);
    }
#undef STAGE
#undef COMPUTE

    // epilogue: D[row=(lane>>4)*4+r][col=lane&15], +bias, nontemporal F32 store
    int lm = lane & 15, kq = lane >> 4;
    int p0r = mt * 256 + wm * 128;
    int b   = nt >> 1;
    int cb2 = (nt & 1) * 256 + wn * 64 + lm;
    size_t outb = (size_t)b * PRED * CH;
#pragma unroll
    for (int i = 0; i < 8; i++) {
#pragma unroll
        for (int r = 0; r < 4; r++) {
            int p = p0r + i * 16 + kq * 4 + r;
            if (p < PRED) {
                float bv = bias[p];
#pragma unroll
                for (int j = 0; j < 4; j++)
                    __builtin_nontemporal_store(acc[i][j][r] + bv,
                                                &out[outb + (size_t)p * CH + cb2 + j * 16]);
            }
        }
    }
}

// ---------------- fallback GEMM (verified r4 kernel, unchanged) ----------------
__global__ void __launch_bounds__(256) gemm_main(
    const short* __restrict__ Kbf, const float* __restrict__ x,
    const float* __restrict__ bias, float* __restrict__ out) {
    __shared__ __align__(16) short ldsA[128 * 32];   // 8 KB
    int t = threadIdx.x;
    int wave = t >> 6, lane = t & 63;
    int mt = blockIdx.x % 6, nt = blockIdx.x / 6;
    int b  = blockIdx.y;
    int wm = wave >> 1, wn = wave & 1;
    const short* Ag = Kbf + (size_t)mt * 128 * 1024;
    const float* xb = x + (size_t)b * SEQ * CH;
    int lm = lane & 15, kq = lane >> 4;
    int cj[4];
    for (int j = 0; j < 4; j++) cj[j] = nt * 128 + wn * 64 + j * 16 + lm;

    floatx4 acc[4][4];
    for (int i = 0; i < 4; i++)
        for (int j = 0; j < 4; j++)
            acc[i][j] = (floatx4){0.f, 0.f, 0.f, 0.f};

    for (int k0 = 0; k0 < 1024; k0 += 32) {
        for (int rdi = 0; rdi < 2; rdi++) {
            int q = rdi * 256 + t;
            int row = q >> 2, ko = (q & 3) * 8;
            async_ld16(Ag + (size_t)row * 1024 + k0 + ko,
                       (char*)ldsA + rdi * 4096 + wave * 1024);
        }
        bf16x8 bfrag[4];
        int krow = k0 + kq * 8;
#pragma unroll
        for (int j = 0; j < 4; j++) {
            const float* xc = xb + (size_t)krow * CH + cj[j];
            bf16x8 bv;
#pragma unroll
            for (int i = 0; i < 8; i++) bv[i] = f2bf(xc[(size_t)i * CH]);
            bfrag[j] = bv;
        }
        __syncthreads();
        bf16x8 af[4];
        for (int i = 0; i < 4; i++)
            af[i] = *(const bf16x8*)&ldsA[(wm * 64 + i * 16 + lm) * 32 + kq * 8];
        for (int i = 0; i < 4; i++)
            for (int j = 0; j < 4; j++)
                acc[i][j] = __builtin_amdgcn_mfma_f32_16x16x32_bf16(af[i], bfrag[j], acc[i][j], 0, 0, 0);
        __syncthreads();
    }

    int p0 = mt * 128 + wm * 64;
    size_t outb = (size_t)b * PRED * CH;
    for (int i = 0; i < 4; i++) {
        for (int r = 0; r < 4; r++) {
            int p = p0 + i * 16 + kq * 4 + r;
            if (p < PRED) {
                float bv = bias[p];
                for (int j = 0; j < 4; j++) {
                    out[outb + (size_t)p * CH + cj[j]] = acc[i][j][r] + bv;
                }
            }
        }
    }
}

extern "C" void kernel_launch(void* const* d_in, const int* in_sizes, int n_in,
                              void* d_out, int out_size, void* d_ws, size_t ws_size,
                              hipStream_t stream) {
    // size-based remap (robust to order); fallback to dict order
    const float* xp = nullptr; const float* wp[2] = {nullptr, nullptr};
    const float* bp[2] = {nullptr, nullptr};
    int wn = 0, bn = 0;
    for (int i = 0; i < n_in; i++) {
        if (in_sizes[i] == 33554432) xp = (const float*)d_in[i];
        else if (in_sizes[i] == 368640 && wn < 2) wp[wn++] = (const float*)d_in[i];
        else if (in_sizes[i] == 720 && bn < 2) bp[bn++] = (const float*)d_in[i];
    }
    if (!xp || wn != 2 || bn != 2) {
        xp = (const float*)d_in[0]; wp[0] = (const float*)d_in[1];
        bp[0] = (const float*)d_in[2]; wp[1] = (const float*)d_in[3];
        bp[1] = (const float*)d_in[4];
    }
    float* out = (float*)d_out;   // F32 output

    char* ws = (char*)d_ws;
    __hip_bfloat16* Kbf = (__hip_bfloat16*)(ws + KBF_OFF);
    float* bias  = (float*)(ws + BIAS_OFF);
    float* WeffS = (float*)(ws + WEFFS_OFF);
    float* WeffT = (float*)(ws + WEFFT_OFF);
    short* xT    = (short*)(ws + XT_OFF);

    bool big = (ws_size >= (size_t)WS_NEED);

    // fused xpose + build_weff: 8192 xpose blocks (only if big) + 192 weff blocks
    prep1<<<(big ? 8192 + 192 : 192), 256, 0, stream>>>(xp, xT, wp[0], wp[1], WeffS, WeffT);
    build_kmat<<<3072, 256, 0, stream>>>(WeffS, WeffT, bp[0], bp[1], Kbf, bias);
    if (big)
        gemm_main_t<<<384, 512, 0, stream>>>((const short*)Kbf, (const short*)xT, bias, out);
    else
        gemm_main<<<dim3(24, 64), 256, 0, stream>>>((const short*)Kbf, xp, bias, out);
}

// Round 6
// 362.352 us; speedup vs baseline: 1.1619x; 1.1619x over previous
//
#include <hip/hip_runtime.h>
#include <hip/hip_bf16.h>
#include <math.h>

// Model: out[b,p,c] = sum_l Kmat[p,l] * x[b,l,c] + bias[p]
// Kmat = Weff_s @ D + (Weff_t - Weff_s) @ (D@T),  Weff = (W @ M)/512
// Output is F32 (resolved r0-r4).
//
// R10 (this round):
//  - UNFUSE prep1 (R9's fusion cost ~+100 µs: 193 µs dispatch, everything
//    idle). xpose and build_weff are separate launches again, byte-level
//    reverts to their individually-verified forms. Dropped the nontemporal
//    x load (never A/B'd, nonzero suspect).
//  - gemm_main_t: KEPT EXACTLY as R9 (256x256x64, 8 waves of 128x64).
//    The validated LDS-pipe model (12cyc/ds_read_b128 per CU, MFMA cyc/SIMD)
//    retro-predicts R6-R8's 17-21% MfmaUtil and puts R9's config at a 27%
//    ceiling, ~30-45 µs — this round measures it cleanly.
//  - build_kmat unchanged (verified).

#define BATCH 64
#define SEQ 1024
#define CH 512
#define PRED 720
#define INV_SQRT2 0.70710678118654752440f

typedef __attribute__((ext_vector_type(4))) float floatx4;
typedef __attribute__((ext_vector_type(8))) short bf16x8;

// ---- workspace layout (bytes) ----
#define KBF_OFF   0ull          // bf16 Kmat[768][1024]     = 1,572,864 B
#define BIAS_OFF  1572864ull    // f32 bias[768]            =     3,072 B
#define WEFFS_OFF 2624512ull    // f32 WeffS[720][512]      = 1,474,560 B
#define WEFFT_OFF 4099072ull    // f32 WeffT[720][512]      = 1,474,560 B
#define XT_OFF    5573632ull    // bf16 xT[64][512][1024]   = 67,108,864 B
#define WS_NEED   (XT_OFF + 67108864ull)

// ---------------- helpers ----------------
__device__ __forceinline__ void async_ld16(const void* g, void* l) {
    __builtin_amdgcn_global_load_lds((const __attribute__((address_space(1))) void*)g,
                                     (__attribute__((address_space(3))) void*)l, 16, 0, 0);
}

__device__ __forceinline__ short f2bf(float f) {
    __hip_bfloat16 h = __float2bfloat16(f);
    return *reinterpret_cast<short*>(&h);
}

// ---------------- xpose: x[b,l,c] f32 -> xT[b,c,l] bf16 (verified R5/R6) ----------------
__global__ void __launch_bounds__(256) xpose(const float* __restrict__ x,
                                             short* __restrict__ xT) {
    __shared__ float lds[64][65];
    int t = threadIdx.x;
    int l0 = blockIdx.x * 64, c0 = blockIdx.y * 64, b = blockIdx.z;
    const float* xb = x + (size_t)b * SEQ * CH;
    int row4 = t >> 4, cq = t & 15;
#pragma unroll
    for (int i = 0; i < 4; i++) {
        int row = row4 + i * 16;
        floatx4 v = *reinterpret_cast<const floatx4*>(
            xb + (size_t)(l0 + row) * CH + c0 + cq * 4);
#pragma unroll
        for (int e = 0; e < 4; e++) lds[row][cq * 4 + e] = v[e];
    }
    __syncthreads();
    size_t outb = (size_t)b * CH * SEQ;
#pragma unroll
    for (int r = 0; r < 2; r++) {
        int u = r * 256 + t;
        int lr = u & 7, c = u >> 3;   // c in 0..63
        bf16x8 s;
#pragma unroll
        for (int e = 0; e < 8; e++) s[e] = f2bf(lds[lr * 8 + e][c]);
        *reinterpret_cast<bf16x8*>(&xT[outb + (size_t)(c0 + c) * SEQ + l0 + lr * 8]) = s;
    }
}

// ---------------- Weff = W @ M/512  (720x512 @ 512x512, f32; verified R8) ----------------
__global__ void __launch_bounds__(256) build_weff(
    const float* __restrict__ Ws_in, const float* __restrict__ Wt_in,
    float* __restrict__ outS, float* __restrict__ outT) {
    const float* W = blockIdx.z ? Wt_in : Ws_in;
    float* out     = blockIdx.z ? outT  : outS;
    int n0 = blockIdx.x * 64;   // 8 tiles
    int p0 = blockIdx.y * 64;   // 12 tiles (last partial: rows 704..719)
    int t  = threadIdx.x;
    int tx = t & 15, ty = t >> 4;
    __shared__ float wlds[32][65];   // [kk][pp], padded
    __shared__ float mlds[32][64];   // [kk][nn]
    float a[4][4] = {};
    for (int kb = 0; kb < 512; kb += 32) {
        __syncthreads();
        {
            int pp = t >> 2, kk0 = (t & 3) * 8;
            int prow = min(p0 + pp, PRED - 1);   // clamp for partial tile
            const float* wsrc = &W[(size_t)prow * 512 + kb + kk0];
#pragma unroll
            for (int e = 0; e < 8; e++) wlds[kk0 + e][pp] = wsrc[e];
        }
        {
            // inline DCT basis: Mw[k][n] = cos(pi*((2n+1)k mod 2048)/1024)*scale/512
            int kk = t >> 3, nn0 = (t & 7) * 8;
            int k = kb + kk;
            float scale = (k == 0) ? 0.04419417382415922f : 0.0625f;
            scale *= (1.0f / 512.0f);
#pragma unroll
            for (int e = 0; e < 8; e++) {
                int n = n0 + nn0 + e;
                int m = ((2 * n + 1) * k) & 2047;
                float ang = (float)m * (float)(M_PI / 1024.0);
                mlds[kk][nn0 + e] = cosf(ang) * scale;
            }
        }
        __syncthreads();
#pragma unroll
        for (int kk = 0; kk < 32; kk++) {
            floatx4 wv = *reinterpret_cast<const floatx4*>(&wlds[kk][ty * 4]);
            floatx4 mv = *reinterpret_cast<const floatx4*>(&mlds[kk][tx * 4]);
#pragma unroll
            for (int i = 0; i < 4; i++)
#pragma unroll
                for (int j = 0; j < 4; j++)
                    a[i][j] += wv[i] * mv[j];
        }
    }
#pragma unroll
    for (int i = 0; i < 4; i++) {
        int p = p0 + ty * 4 + i;
        if (p < PRED) {
            floatx4 v = {a[i][0], a[i][1], a[i][2], a[i][3]};
            *reinterpret_cast<floatx4*>(&out[(size_t)p * 512 + n0 + tx * 4]) = v;
        }
    }
}

// ---------------- Kmat build (banded D@T analytic, verified) ----------------
__device__ __forceinline__ int tcnt(int j, int l) {
    if (l == 0)    return max(0, 13 - j);
    if (l == 1023) return max(0, j - 1010);
    int d = l - j; if (d < 0) d = -d;
    return (d <= 12) ? 1 : 0;
}

__global__ void build_kmat(const float* __restrict__ Ws, const float* __restrict__ Wt,
                           const float* __restrict__ bs, const float* __restrict__ bt,
                           __hip_bfloat16* __restrict__ Kbf, float* __restrict__ bias) {
    int idx = blockIdx.x * 256 + threadIdx.x;   // 768*1024
    int p = idx >> 10, l = idx & 1023;
    if (p >= PRED) { Kbf[idx] = __float2bfloat16(0.0f); return; }
    if (l == 0) bias[p] = bs[p] + bt[p];
    float v = INV_SQRT2 * Ws[(size_t)p * 512 + (l >> 1)];
    int jlo = max(0, l - 12), jhi = min(1023, l + 12);
    float acc = 0.f;
    for (int n = (jlo >> 1); n <= (jhi >> 1); n++) {
        int c = tcnt(2 * n, l) + tcnt(2 * n + 1, l);
        if (c) acc += (Wt[(size_t)p * 512 + n] - Ws[(size_t)p * 512 + n]) * (float)c;
    }
    v += acc * (INV_SQRT2 / 25.0f);
    Kbf[idx] = __float2bfloat16(v);
}

// ---------------- main GEMM: BM=256 BN=256 BK=64, 8 waves of 128x64 (R9, unchanged) ----------------
__global__ void __launch_bounds__(512, 2) gemm_main_t(
    const short* __restrict__ Kbf, const short* __restrict__ xT,
    const float* __restrict__ bias, float* __restrict__ out) {
    // [buf 0..1][A 32KB | B 32KB] = 128 KB
    __shared__ __align__(16) short ldsbuf[2 * 32768];
    int t = threadIdx.x;
    int wave = t >> 6, lane = t & 63;
    int bid = blockIdx.x;                       // 384 blocks
    int work = (bid & 7) * 48 + (bid >> 3);     // XCD-chunked, bijective
    int mt = work % 3;                          // A panel (256 rows)
    int nt = work / 3;                          // B panel (256 n-rows), 0..127
    int wm = wave >> 2, wn = wave & 3;          // 2x4 waves of 128x64
    const short* Ag = Kbf + (size_t)mt * 256 * 1024;
    const short* Bg = xT + (size_t)nt * 256 * 1024;

    size_t so[4];
#pragma unroll
    for (int a = 0; a < 4; a++) {
        int s = a * 512 + t;
        so[a] = (size_t)(((s >> 7) << 4) + (s & 15)) * 1024
              + ((s >> 6) & 1) * 32 + ((s >> 4) & 3) * 8;
    }

    floatx4 acc[8][4];
#pragma unroll
    for (int i = 0; i < 8; i++)
#pragma unroll
        for (int j = 0; j < 4; j++)
            acc[i][j] = (floatx4){0.f, 0.f, 0.f, 0.f};

#define STAGE(bufidx, k0v)                                                     \
    {                                                                          \
        char* base_ = (char*)ldsbuf + (bufidx) * 65536;                        \
        _Pragma("unroll")                                                      \
        for (int a = 0; a < 4; a++)                                            \
            async_ld16(Ag + so[a] + (k0v), base_ + a * 8192 + wave * 1024);    \
        _Pragma("unroll")                                                      \
        for (int a = 0; a < 4; a++)                                            \
            async_ld16(Bg + so[a] + (k0v),                                     \
                       base_ + 32768 + a * 8192 + wave * 1024);                \
    }

#define COMPUTE(cbp)                                                           \
    {                                                                          \
        _Pragma("unroll")                                                      \
        for (int ks = 0; ks < 2; ks++) {                                       \
            bf16x8 af[8], bf[4];                                               \
            _Pragma("unroll")                                                  \
            for (int i = 0; i < 8; i++)                                        \
                af[i] = *reinterpret_cast<const bf16x8*>(                      \
                    (cbp) + ((wm * 8 + i) << 11) + (ks << 10) + (lane << 4));  \
            _Pragma("unroll")                                                  \
            for (int j = 0; j < 4; j++)                                        \
                bf[j] = *reinterpret_cast<const bf16x8*>(                      \
                    (cbp) + 32768 + ((wn * 4 + j) << 11) + (ks << 10) +        \
                    (lane << 4));                                              \
            __builtin_amdgcn_s_setprio(1);                                     \
            _Pragma("unroll")                                                  \
            for (int i = 0; i < 8; i++)                                        \
                _Pragma("unroll")                                              \
                for (int j = 0; j < 4; j++)                                    \
                    acc[i][j] = __builtin_amdgcn_mfma_f32_16x16x32_bf16(       \
                        af[i], bf[j], acc[i][j], 0, 0, 0);                     \
            __builtin_amdgcn_s_setprio(0);                                     \
        }                                                                      \
    }

    // prologue: stage k-tiles 0,1 into bufs 0,1
    STAGE(0, 0);
    STAGE(1, 64);

    for (int it = 0; it < 15; ++it) {
        asm volatile("s_waitcnt vmcnt(8)" ::: "memory");
        __builtin_amdgcn_s_barrier();
        __builtin_amdgcn_sched_barrier(0);
        const char* cbp = (const char*)ldsbuf + (it & 1) * 65536;
        COMPUTE(cbp);
        __builtin_amdgcn_sched_barrier(0);
        __builtin_amdgcn_s_barrier();           // all waves done reading buf[it&1]
        __builtin_amdgcn_sched_barrier(0);
        if (it < 14) STAGE(it & 1, (it + 2) * 64);
    }
    // peeled last k-tile (15) from buf 1
    asm volatile("s_waitcnt vmcnt(0)" ::: "memory");
    __builtin_amdgcn_s_barrier();
    __builtin_amdgcn_sched_barrier(0);
    {
        const char* cbp = (const char*)ldsbuf + 65536;
        COMPUTE(cbp);
    }
#undef STAGE
#undef COMPUTE

    // epilogue: D[row=(lane>>4)*4+r][col=lane&15], +bias, nontemporal F32 store
    int lm = lane & 15, kq = lane >> 4;
    int p0r = mt * 256 + wm * 128;
    int b   = nt >> 1;
    int cb2 = (nt & 1) * 256 + wn * 64 + lm;
    size_t outb = (size_t)b * PRED * CH;
#pragma unroll
    for (int i = 0; i < 8; i++) {
#pragma unroll
        for (int r = 0; r < 4; r++) {
            int p = p0r + i * 16 + kq * 4 + r;
            if (p < PRED) {
                float bv = bias[p];
#pragma unroll
                for (int j = 0; j < 4; j++)
                    __builtin_nontemporal_store(acc[i][j][r] + bv,
                                                &out[outb + (size_t)p * CH + cb2 + j * 16]);
            }
        }
    }
}

// ---------------- fallback GEMM (verified r4 kernel, unchanged) ----------------
__global__ void __launch_bounds__(256) gemm_main(
    const short* __restrict__ Kbf, const float* __restrict__ x,
    const float* __restrict__ bias, float* __restrict__ out) {
    __shared__ __align__(16) short ldsA[128 * 32];   // 8 KB
    int t = threadIdx.x;
    int wave = t >> 6, lane = t & 63;
    int mt = blockIdx.x % 6, nt = blockIdx.x / 6;
    int b  = blockIdx.y;
    int wm = wave >> 1, wn = wave & 1;
    const short* Ag = Kbf + (size_t)mt * 128 * 1024;
    const float* xb = x + (size_t)b * SEQ * CH;
    int lm = lane & 15, kq = lane >> 4;
    int cj[4];
    for (int j = 0; j < 4; j++) cj[j] = nt * 128 + wn * 64 + j * 16 + lm;

    floatx4 acc[4][4];
    for (int i = 0; i < 4; i++)
        for (int j = 0; j < 4; j++)
            acc[i][j] = (floatx4){0.f, 0.f, 0.f, 0.f};

    for (int k0 = 0; k0 < 1024; k0 += 32) {
        for (int rdi = 0; rdi < 2; rdi++) {
            int q = rdi * 256 + t;
            int row = q >> 2, ko = (q & 3) * 8;
            async_ld16(Ag + (size_t)row * 1024 + k0 + ko,
                       (char*)ldsA + rdi * 4096 + wave * 1024);
        }
        bf16x8 bfrag[4];
        int krow = k0 + kq * 8;
#pragma unroll
        for (int j = 0; j < 4; j++) {
            const float* xc = xb + (size_t)krow * CH + cj[j];
            bf16x8 bv;
#pragma unroll
            for (int i = 0; i < 8; i++) bv[i] = f2bf(xc[(size_t)i * CH]);
            bfrag[j] = bv;
        }
        __syncthreads();
        bf16x8 af[4];
        for (int i = 0; i < 4; i++)
            af[i] = *(const bf16x8*)&ldsA[(wm * 64 + i * 16 + lm) * 32 + kq * 8];
        for (int i = 0; i < 4; i++)
            for (int j = 0; j < 4; j++)
                acc[i][j] = __builtin_amdgcn_mfma_f32_16x16x32_bf16(af[i], bfrag[j], acc[i][j], 0, 0, 0);
        __syncthreads();
    }

    int p0 = mt * 128 + wm * 64;
    size_t outb = (size_t)b * PRED * CH;
    for (int i = 0; i < 4; i++) {
        for (int r = 0; r < 4; r++) {
            int p = p0 + i * 16 + kq * 4 + r;
            if (p < PRED) {
                float bv = bias[p];
                for (int j = 0; j < 4; j++) {
                    out[outb + (size_t)p * CH + cj[j]] = acc[i][j][r] + bv;
                }
            }
        }
    }
}

extern "C" void kernel_launch(void* const* d_in, const int* in_sizes, int n_in,
                              void* d_out, int out_size, void* d_ws, size_t ws_size,
                              hipStream_t stream) {
    // size-based remap (robust to order); fallback to dict order
    const float* xp = nullptr; const float* wp[2] = {nullptr, nullptr};
    const float* bp[2] = {nullptr, nullptr};
    int wn = 0, bn = 0;
    for (int i = 0; i < n_in; i++) {
        if (in_sizes[i] == 33554432) xp = (const float*)d_in[i];
        else if (in_sizes[i] == 368640 && wn < 2) wp[wn++] = (const float*)d_in[i];
        else if (in_sizes[i] == 720 && bn < 2) bp[bn++] = (const float*)d_in[i];
    }
    if (!xp || wn != 2 || bn != 2) {
        xp = (const float*)d_in[0]; wp[0] = (const float*)d_in[1];
        bp[0] = (const float*)d_in[2]; wp[1] = (const float*)d_in[3];
        bp[1] = (const float*)d_in[4];
    }
    float* out = (float*)d_out;   // F32 output

    char* ws = (char*)d_ws;
    __hip_bfloat16* Kbf = (__hip_bfloat16*)(ws + KBF_OFF);
    float* bias  = (float*)(ws + BIAS_OFF);
    float* WeffS = (float*)(ws + WEFFS_OFF);
    float* WeffT = (float*)(ws + WEFFT_OFF);
    short* xT    = (short*)(ws + XT_OFF);

    bool big = (ws_size >= (size_t)WS_NEED);

    if (big) xpose<<<dim3(16, 8, 64), 256, 0, stream>>>(xp, xT);
    build_weff<<<dim3(8, 12, 2), 256, 0, stream>>>(wp[0], wp[1], WeffS, WeffT);
    build_kmat<<<3072, 256, 0, stream>>>(WeffS, WeffT, bp[0], bp[1], Kbf, bias);
    if (big)
        gemm_main_t<<<384, 512, 0, stream>>>((const short*)Kbf, (const short*)xT, bias, out);
    else
        gemm_main<<<dim3(24, 64), 256, 0, stream>>>((const short*)Kbf, xp, bias, out);
}

// Round 7
// 356.128 us; speedup vs baseline: 1.1822x; 1.0175x over previous
//
#include <hip/hip_runtime.h>
#include <hip/hip_bf16.h>
#include <math.h>

// Model: out[b,p,c] = sum_l Kmat[p,l] * x[b,l,c] + bias[p]
// Kmat = Weff_s @ D + (Weff_t - Weff_s) @ (D@T),  Weff = (W @ M)/512
// Output is F32 (resolved r0-r4).
//
// R11 (this round):
//  - gemm_main_t: 8-phase interleave port (catalog T3+T4, m201 template).
//    R10 measured: no pipe saturated (LDS 32%, HBM 19%, MFMA 21%) ->
//    serialization-bound monolithic k-step. New K-loop: per K-tile 4 phases,
//    each {ds-read subtile || stage 1 half-tile -> barrier -> lgkmcnt(0) ->
//    16 MFMA setprio-wrapped -> barrier}; vmcnt(2) once per K-tile placed
//    BEFORE the group-end barrier (vmcnt->barrier = cross-wave sound).
//    Stage schedule: P1:A1(g+1) P2:B0(g+1) P3:B1(g+1) P4:A0(g+2); P4 has no
//    LDS reads so staging the current buffer's A0 region there is race-free
//    (all reads of it end at P3's trailing barrier). Linear staging layout
//    kept (0 bank conflicts measured -> no swizzle needed).
//    Per-accumulator k-order unchanged -> bit-identical output.
//  - xpose / build_weff / build_kmat / fallback: unchanged (verified R10).

#define BATCH 64
#define SEQ 1024
#define CH 512
#define PRED 720
#define INV_SQRT2 0.70710678118654752440f

typedef __attribute__((ext_vector_type(4))) float floatx4;
typedef __attribute__((ext_vector_type(8))) short bf16x8;

// ---- workspace layout (bytes) ----
#define KBF_OFF   0ull          // bf16 Kmat[768][1024]     = 1,572,864 B
#define BIAS_OFF  1572864ull    // f32 bias[768]            =     3,072 B
#define WEFFS_OFF 2624512ull    // f32 WeffS[720][512]      = 1,474,560 B
#define WEFFT_OFF 4099072ull    // f32 WeffT[720][512]      = 1,474,560 B
#define XT_OFF    5573632ull    // bf16 xT[64][512][1024]   = 67,108,864 B
#define WS_NEED   (XT_OFF + 67108864ull)

// ---------------- helpers ----------------
__device__ __forceinline__ void async_ld16(const void* g, void* l) {
    __builtin_amdgcn_global_load_lds((const __attribute__((address_space(1))) void*)g,
                                     (__attribute__((address_space(3))) void*)l, 16, 0, 0);
}

__device__ __forceinline__ short f2bf(float f) {
    __hip_bfloat16 h = __float2bfloat16(f);
    return *reinterpret_cast<short*>(&h);
}

// ---------------- xpose: x[b,l,c] f32 -> xT[b,c,l] bf16 (verified) ----------------
__global__ void __launch_bounds__(256) xpose(const float* __restrict__ x,
                                             short* __restrict__ xT) {
    __shared__ float lds[64][65];
    int t = threadIdx.x;
    int l0 = blockIdx.x * 64, c0 = blockIdx.y * 64, b = blockIdx.z;
    const float* xb = x + (size_t)b * SEQ * CH;
    int row4 = t >> 4, cq = t & 15;
#pragma unroll
    for (int i = 0; i < 4; i++) {
        int row = row4 + i * 16;
        floatx4 v = *reinterpret_cast<const floatx4*>(
            xb + (size_t)(l0 + row) * CH + c0 + cq * 4);
#pragma unroll
        for (int e = 0; e < 4; e++) lds[row][cq * 4 + e] = v[e];
    }
    __syncthreads();
    size_t outb = (size_t)b * CH * SEQ;
#pragma unroll
    for (int r = 0; r < 2; r++) {
        int u = r * 256 + t;
        int lr = u & 7, c = u >> 3;   // c in 0..63
        bf16x8 s;
#pragma unroll
        for (int e = 0; e < 8; e++) s[e] = f2bf(lds[lr * 8 + e][c]);
        *reinterpret_cast<bf16x8*>(&xT[outb + (size_t)(c0 + c) * SEQ + l0 + lr * 8]) = s;
    }
}

// ---------------- Weff = W @ M/512  (verified R8/R10) ----------------
__global__ void __launch_bounds__(256) build_weff(
    const float* __restrict__ Ws_in, const float* __restrict__ Wt_in,
    float* __restrict__ outS, float* __restrict__ outT) {
    const float* W = blockIdx.z ? Wt_in : Ws_in;
    float* out     = blockIdx.z ? outT  : outS;
    int n0 = blockIdx.x * 64;   // 8 tiles
    int p0 = blockIdx.y * 64;   // 12 tiles (last partial: rows 704..719)
    int t  = threadIdx.x;
    int tx = t & 15, ty = t >> 4;
    __shared__ float wlds[32][65];   // [kk][pp], padded
    __shared__ float mlds[32][64];   // [kk][nn]
    float a[4][4] = {};
    for (int kb = 0; kb < 512; kb += 32) {
        __syncthreads();
        {
            int pp = t >> 2, kk0 = (t & 3) * 8;
            int prow = min(p0 + pp, PRED - 1);   // clamp for partial tile
            const float* wsrc = &W[(size_t)prow * 512 + kb + kk0];
#pragma unroll
            for (int e = 0; e < 8; e++) wlds[kk0 + e][pp] = wsrc[e];
        }
        {
            // inline DCT basis: Mw[k][n] = cos(pi*((2n+1)k mod 2048)/1024)*scale/512
            int kk = t >> 3, nn0 = (t & 7) * 8;
            int k = kb + kk;
            float scale = (k == 0) ? 0.04419417382415922f : 0.0625f;
            scale *= (1.0f / 512.0f);
#pragma unroll
            for (int e = 0; e < 8; e++) {
                int n = n0 + nn0 + e;
                int m = ((2 * n + 1) * k) & 2047;
                float ang = (float)m * (float)(M_PI / 1024.0);
                mlds[kk][nn0 + e] = cosf(ang) * scale;
            }
        }
        __syncthreads();
#pragma unroll
        for (int kk = 0; kk < 32; kk++) {
            floatx4 wv = *reinterpret_cast<const floatx4*>(&wlds[kk][ty * 4]);
            floatx4 mv = *reinterpret_cast<const floatx4*>(&mlds[kk][tx * 4]);
#pragma unroll
            for (int i = 0; i < 4; i++)
#pragma unroll
                for (int j = 0; j < 4; j++)
                    a[i][j] += wv[i] * mv[j];
        }
    }
#pragma unroll
    for (int i = 0; i < 4; i++) {
        int p = p0 + ty * 4 + i;
        if (p < PRED) {
            floatx4 v = {a[i][0], a[i][1], a[i][2], a[i][3]};
            *reinterpret_cast<floatx4*>(&out[(size_t)p * 512 + n0 + tx * 4]) = v;
        }
    }
}

// ---------------- Kmat build (banded D@T analytic, verified) ----------------
__device__ __forceinline__ int tcnt(int j, int l) {
    if (l == 0)    return max(0, 13 - j);
    if (l == 1023) return max(0, j - 1010);
    int d = l - j; if (d < 0) d = -d;
    return (d <= 12) ? 1 : 0;
}

__global__ void build_kmat(const float* __restrict__ Ws, const float* __restrict__ Wt,
                           const float* __restrict__ bs, const float* __restrict__ bt,
                           __hip_bfloat16* __restrict__ Kbf, float* __restrict__ bias) {
    int idx = blockIdx.x * 256 + threadIdx.x;   // 768*1024
    int p = idx >> 10, l = idx & 1023;
    if (p >= PRED) { Kbf[idx] = __float2bfloat16(0.0f); return; }
    if (l == 0) bias[p] = bs[p] + bt[p];
    float v = INV_SQRT2 * Ws[(size_t)p * 512 + (l >> 1)];
    int jlo = max(0, l - 12), jhi = min(1023, l + 12);
    float acc = 0.f;
    for (int n = (jlo >> 1); n <= (jhi >> 1); n++) {
        int c = tcnt(2 * n, l) + tcnt(2 * n + 1, l);
        if (c) acc += (Wt[(size_t)p * 512 + n] - Ws[(size_t)p * 512 + n]) * (float)c;
    }
    v += acc * (INV_SQRT2 / 25.0f);
    Kbf[idx] = __float2bfloat16(v);
}

// ---------------- main GEMM: 256x256x64, 8 waves, 8-phase schedule ----------------
// A = Kbf[768][1024], B = xT viewed [32768][1024], out[b][p][c].
// 2 LDS buffers of 64 KB; tile T lives in buf[T&1]. Half-tiles (16 KB,
// 2 global_load_lds/thread): A0 = A rows 0-127, A1 = rows 128-255, B0, B1.
// Tile G's halves are staged at: A0 @ P4(G-2), A1/B0/B1 @ P1/P2/P3(G-1).
// Group-end: vmcnt(2) (leaves only A0(G+2) in flight) THEN barrier -> every
// wave's tile-(G+1) writes have landed before any wave reads them.
__global__ void __launch_bounds__(512, 2) gemm_main_t(
    const short* __restrict__ Kbf, const short* __restrict__ xT,
    const float* __restrict__ bias, float* __restrict__ out) {
    __shared__ __align__(16) short ldsbuf[2 * 32768];   // 128 KB
    int t = threadIdx.x;
    int wave = t >> 6, lane = t & 63;
    int bid = blockIdx.x;                       // 384 blocks
    int work = (bid & 7) * 48 + (bid >> 3);     // XCD-chunked, bijective
    int mt = work % 3;                          // A panel (256 rows)
    int nt = work / 3;                          // B panel (256 n-rows), 0..127
    int wm = wave >> 2, wn = wave & 3;          // 2x4 waves of 128x64
    const short* Ag = Kbf + (size_t)mt * 256 * 1024;
    const short* Bg = xT + (size_t)nt * 256 * 1024;

    // staged-slot source offsets: slot s (16B) holds row ((s>>7)<<4)+(s&15),
    // k-offset ((s>>6)&1)*32 + ((s>>4)&3)*8. Chunk a = slots [a*512, a*512+512).
    size_t so[4];
#pragma unroll
    for (int a = 0; a < 4; a++) {
        int s = a * 512 + t;
        so[a] = (size_t)(((s >> 7) << 4) + (s & 15)) * 1024
              + ((s >> 6) & 1) * 32 + ((s >> 4) & 3) * 8;
    }

    floatx4 acc[8][4];
#pragma unroll
    for (int i = 0; i < 8; i++)
#pragma unroll
        for (int j = 0; j < 4; j++)
            acc[i][j] = (floatx4){0.f, 0.f, 0.f, 0.f};

    bf16x8 af[4][2], bf[4][2];

#define MFMA16(I0, J0)                                                         \
    __builtin_amdgcn_s_setprio(1);                                             \
    _Pragma("unroll")                                                          \
    for (int i = 0; i < 4; i++)                                                \
        _Pragma("unroll")                                                      \
        for (int j = 0; j < 2; j++)                                            \
            _Pragma("unroll")                                                  \
            for (int ks = 0; ks < 2; ks++)                                     \
                acc[(I0) + i][(J0) + j] =                                      \
                    __builtin_amdgcn_mfma_f32_16x16x32_bf16(                   \
                        af[i][ks], bf[(J0) + j][ks],                           \
                        acc[(I0) + i][(J0) + j], 0, 0, 0);                     \
    __builtin_amdgcn_s_setprio(0);

#define PH_BAR()                                                               \
    __builtin_amdgcn_s_barrier();                                              \
    asm volatile("s_waitcnt lgkmcnt(0)" ::: "memory");                         \
    __builtin_amdgcn_sched_barrier(0);

#define PH_END()                                                               \
    __builtin_amdgcn_s_barrier();                                              \
    __builtin_amdgcn_sched_barrier(0);

    // GROUP(G): compute tile G; S123: stage A1/B0/B1(G+1); S4: stage A0(G+2);
    // TAILMODE: 2 -> vmcnt(2)+bar, 0 -> vmcnt(0)+bar, -1 -> none.
#define GROUP(G, S123, S4, TAILMODE)                                           \
    {                                                                          \
        const char* cb = (const char*)ldsbuf + ((G) & 1) * 65536;              \
        char* nb = (char*)ldsbuf + (((G) + 1) & 1) * 65536;                    \
        char* s2 = (char*)ldsbuf + ((G) & 1) * 65536;                          \
        /* P1: af[0..3], bf[0..1]; stage A1(G+1) */                            \
        _Pragma("unroll")                                                      \
        for (int i = 0; i < 4; i++)                                            \
            _Pragma("unroll")                                                  \
            for (int ks = 0; ks < 2; ks++)                                     \
                af[i][ks] = *reinterpret_cast<const bf16x8*>(                  \
                    cb + ((wm * 8 + i) << 11) + (ks << 10) + (lane << 4));     \
        _Pragma("unroll")                                                      \
        for (int j = 0; j < 2; j++)                                            \
            _Pragma("unroll")                                                  \
            for (int ks = 0; ks < 2; ks++)                                     \
                bf[j][ks] = *reinterpret_cast<const bf16x8*>(                  \
                    cb + 32768 + ((wn * 4 + j) << 11) + (ks << 10) +           \
                    (lane << 4));                                              \
        if (S123) {                                                            \
            async_ld16(Ag + so[2] + ((G) + 1) * 64,                            \
                       nb + 2 * 8192 + wave * 1024);                           \
            async_ld16(Ag + so[3] + ((G) + 1) * 64,                            \
                       nb + 3 * 8192 + wave * 1024);                           \
        }                                                                      \
        PH_BAR()                                                               \
        MFMA16(0, 0)                                                           \
        PH_END()                                                               \
        /* P2: bf[2..3]; stage B0(G+1) */                                      \
        _Pragma("unroll")                                                      \
        for (int j = 2; j < 4; j++)                                            \
            _Pragma("unroll")                                                  \
            for (int ks = 0; ks < 2; ks++)                                     \
                bf[j][ks] = *reinterpret_cast<const bf16x8*>(                  \
                    cb + 32768 + ((wn * 4 + j) << 11) + (ks << 10) +           \
                    (lane << 4));                                              \
        if (S123) {                                                            \
            async_ld16(Bg + so[0] + ((G) + 1) * 64,                            \
                       nb + 32768 + 0 * 8192 + wave * 1024);                   \
            async_ld16(Bg + so[1] + ((G) + 1) * 64,                            \
                       nb + 32768 + 1 * 8192 + wave * 1024);                   \
        }                                                                      \
        PH_BAR()                                                               \
        MFMA16(0, 2)                                                           \
        PH_END()                                                               \
        /* P3: af[4..7] (reuse regs); stage B1(G+1) */                         \
        _Pragma("unroll")                                                      \
        for (int i = 0; i < 4; i++)                                            \
            _Pragma("unroll")                                                  \
            for (int ks = 0; ks < 2; ks++)                                     \
                af[i][ks] = *reinterpret_cast<const bf16x8*>(                  \
                    cb + ((wm * 8 + 4 + i) << 11) + (ks << 10) + (lane << 4)); \
        if (S123) {                                                            \
            async_ld16(Bg + so[2] + ((G) + 1) * 64,                            \
                       nb + 32768 + 2 * 8192 + wave * 1024);                   \
            async_ld16(Bg + so[3] + ((G) + 1) * 64,                            \
                       nb + 32768 + 3 * 8192 + wave * 1024);                   \
        }                                                                      \
        PH_BAR()                                                               \
        MFMA16(4, 2)                                                           \
        PH_END()                                                               \
        /* P4: no LDS reads; stage A0(G+2) into current buffer (safe: all */   \
        /* reads of it ended at P3's trailing barrier); MFMA; tail vmcnt */    \
        if (S4) {                                                              \
            async_ld16(Ag + so[0] + ((G) + 2) * 64,                            \
                       s2 + 0 * 8192 + wave * 1024);                           \
            async_ld16(Ag + so[1] + ((G) + 2) * 64,                            \
                       s2 + 1 * 8192 + wave * 1024);                           \
        }                                                                      \
        MFMA16(4, 0)                                                           \
        if ((TAILMODE) == 2) {                                                 \
            asm volatile("s_waitcnt vmcnt(2)" ::: "memory");                   \
            __builtin_amdgcn_s_barrier();                                      \
            __builtin_amdgcn_sched_barrier(0);                                 \
        } else if ((TAILMODE) == 0) {                                          \
            asm volatile("s_waitcnt vmcnt(0)" ::: "memory");                   \
            __builtin_amdgcn_s_barrier();                                      \
            __builtin_amdgcn_sched_barrier(0);                                 \
        }                                                                      \
    }

    // prologue: T0 {A0,A1,B0,B1} -> buf0, T1 {A0} -> buf1; vmcnt(2)+barrier
    {
        char* b0 = (char*)ldsbuf;
        char* b1 = (char*)ldsbuf + 65536;
#pragma unroll
        for (int a = 0; a < 4; a++)
            async_ld16(Ag + so[a], b0 + a * 8192 + wave * 1024);
#pragma unroll
        for (int a = 0; a < 4; a++)
            async_ld16(Bg + so[a], b0 + 32768 + a * 8192 + wave * 1024);
        async_ld16(Ag + so[0] + 64, b1 + 0 * 8192 + wave * 1024);
        async_ld16(Ag + so[1] + 64, b1 + 1 * 8192 + wave * 1024);
        asm volatile("s_waitcnt vmcnt(2)" ::: "memory");
        __builtin_amdgcn_s_barrier();
        __builtin_amdgcn_sched_barrier(0);
    }

    for (int g = 0; g < 14; ++g) GROUP(g, 1, 1, 2);
    GROUP(14, 1, 0, 0)
    GROUP(15, 0, 0, -1)

#undef GROUP
#undef PH_BAR
#undef PH_END
#undef MFMA16

    // epilogue: D[row=(lane>>4)*4+r][col=lane&15], +bias, nontemporal F32 store
    int lm = lane & 15, kq = lane >> 4;
    int p0r = mt * 256 + wm * 128;
    int b   = nt >> 1;
    int cb2 = (nt & 1) * 256 + wn * 64 + lm;
    size_t outb = (size_t)b * PRED * CH;
#pragma unroll
    for (int i = 0; i < 8; i++) {
#pragma unroll
        for (int r = 0; r < 4; r++) {
            int p = p0r + i * 16 + kq * 4 + r;
            if (p < PRED) {
                float bv = bias[p];
#pragma unroll
                for (int j = 0; j < 4; j++)
                    __builtin_nontemporal_store(acc[i][j][r] + bv,
                                                &out[outb + (size_t)p * CH + cb2 + j * 16]);
            }
        }
    }
}

// ---------------- fallback GEMM (verified r4 kernel, unchanged) ----------------
__global__ void __launch_bounds__(256) gemm_main(
    const short* __restrict__ Kbf, const float* __restrict__ x,
    const float* __restrict__ bias, float* __restrict__ out) {
    __shared__ __align__(16) short ldsA[128 * 32];   // 8 KB
    int t = threadIdx.x;
    int wave = t >> 6, lane = t & 63;
    int mt = blockIdx.x % 6, nt = blockIdx.x / 6;
    int b  = blockIdx.y;
    int wm = wave >> 1, wn = wave & 1;
    const short* Ag = Kbf + (size_t)mt * 128 * 1024;
    const float* xb = x + (size_t)b * SEQ * CH;
    int lm = lane & 15, kq = lane >> 4;
    int cj[4];
    for (int j = 0; j < 4; j++) cj[j] = nt * 128 + wn * 64 + j * 16 + lm;

    floatx4 acc[4][4];
    for (int i = 0; i < 4; i++)
        for (int j = 0; j < 4; j++)
            acc[i][j] = (floatx4){0.f, 0.f, 0.f, 0.f};

    for (int k0 = 0; k0 < 1024; k0 += 32) {
        for (int rdi = 0; rdi < 2; rdi++) {
            int q = rdi * 256 + t;
            int row = q >> 2, ko = (q & 3) * 8;
            async_ld16(Ag + (size_t)row * 1024 + k0 + ko,
                       (char*)ldsA + rdi * 4096 + wave * 1024);
        }
        bf16x8 bfrag[4];
        int krow = k0 + kq * 8;
#pragma unroll
        for (int j = 0; j < 4; j++) {
            const float* xc = xb + (size_t)krow * CH + cj[j];
            bf16x8 bv;
#pragma unroll
            for (int i = 0; i < 8; i++) bv[i] = f2bf(xc[(size_t)i * CH]);
            bfrag[j] = bv;
        }
        __syncthreads();
        bf16x8 af[4];
        for (int i = 0; i < 4; i++)
            af[i] = *(const bf16x8*)&ldsA[(wm * 64 + i * 16 + lm) * 32 + kq * 8];
        for (int i = 0; i < 4; i++)
            for (int j = 0; j < 4; j++)
                acc[i][j] = __builtin_amdgcn_mfma_f32_16x16x32_bf16(af[i], bfrag[j], acc[i][j], 0, 0, 0);
        __syncthreads();
    }

    int p0 = mt * 128 + wm * 64;
    size_t outb = (size_t)b * PRED * CH;
    for (int i = 0; i < 4; i++) {
        for (int r = 0; r < 4; r++) {
            int p = p0 + i * 16 + kq * 4 + r;
            if (p < PRED) {
                float bv = bias[p];
                for (int j = 0; j < 4; j++) {
                    out[outb + (size_t)p * CH + cj[j]] = acc[i][j][r] + bv;
                }
            }
        }
    }
}

extern "C" void kernel_launch(void* const* d_in, const int* in_sizes, int n_in,
                              void* d_out, int out_size, void* d_ws, size_t ws_size,
                              hipStream_t stream) {
    // size-based remap (robust to order); fallback to dict order
    const float* xp = nullptr; const float* wp[2] = {nullptr, nullptr};
    const float* bp[2] = {nullptr, nullptr};
    int wn = 0, bn = 0;
    for (int i = 0; i < n_in; i++) {
        if (in_sizes[i] == 33554432) xp = (const float*)d_in[i];
        else if (in_sizes[i] == 368640 && wn < 2) wp[wn++] = (const float*)d_in[i];
        else if (in_sizes[i] == 720 && bn < 2) bp[bn++] = (const float*)d_in[i];
    }
    if (!xp || wn != 2 || bn != 2) {
        xp = (const float*)d_in[0]; wp[0] = (const float*)d_in[1];
        bp[0] = (const float*)d_in[2]; wp[1] = (const float*)d_in[3];
        bp[1] = (const float*)d_in[4];
    }
    float* out = (float*)d_out;   // F32 output

    char* ws = (char*)d_ws;
    __hip_bfloat16* Kbf = (__hip_bfloat16*)(ws + KBF_OFF);
    float* bias  = (float*)(ws + BIAS_OFF);
    float* WeffS = (float*)(ws + WEFFS_OFF);
    float* WeffT = (float*)(ws + WEFFT_OFF);
    short* xT    = (short*)(ws + XT_OFF);

    bool big = (ws_size >= (size_t)WS_NEED);

    if (big) xpose<<<dim3(16, 8, 64), 256, 0, stream>>>(xp, xT);
    build_weff<<<dim3(8, 12, 2), 256, 0, stream>>>(wp[0], wp[1], WeffS, WeffT);
    build_kmat<<<3072, 256, 0, stream>>>(WeffS, WeffT, bp[0], bp[1], Kbf, bias);
    if (big)
        gemm_main_t<<<384, 512, 0, stream>>>((const short*)Kbf, (const short*)xT, bias, out);
    else
        gemm_main<<<dim3(24, 64), 256, 0, stream>>>((const short*)Kbf, xp, bias, out);
}